// Round 1
// baseline (194.749 us; speedup 1.0000x reference)
//
#include <hip/hip_runtime.h>

// MHA forward, MI355X gfx950.
// Shapes: b=8, heads=8 -> bh=64; S=1024; head_dim=64. fp32 in/out, bf16 MFMA inside.
// Memory layout per bh (from reference reshape): X[d][s] (d-major, contiguous in s).
// Mask: M[b][q][k], values in {0, -10000}; keep iff value == 0. Softmax over kept keys.

#define SEQ   1024
#define HD    64
#define QB    64      // q-rows per block
#define KB    64      // keys per K-tile
#define PITCH 68      // LDS pitch in halfwords: 136B rows (8B-aligned), odd dword stride -> ~2-way banks

typedef __attribute__((ext_vector_type(8))) short short8;   // 8 bf16 (4 VGPRs)
typedef __attribute__((ext_vector_type(4))) float floatx4;  // MFMA accumulator

union F8 { short8 s8; uint2 u2[2]; };

__device__ __forceinline__ ushort f2bf(float f) {
    union { float f; unsigned u; } cv; cv.f = f;
    unsigned u = cv.u + 0x7FFFu + ((cv.u >> 16) & 1u);   // RNE, no NaN inputs here
    return (ushort)(u >> 16);
}

__global__ __launch_bounds__(256)
void mha_fwd_kernel(const float* __restrict__ Q, const float* __restrict__ K,
                    const float* __restrict__ V, const float* __restrict__ M,
                    float* __restrict__ O)
{
    __shared__ ushort ks[KB][PITCH];      // K-tile transposed: [k][d]  (QK B-operand: c=d contiguous)
    __shared__ ushort vs[HD][PITCH];      // V-tile native:      [d][k] (PV B-operand: c=k contiguous)
    __shared__ ushort qs[QB][PITCH];      // Q-tile transposed:  [q][d] (A-operand: c=d contiguous)
    __shared__ ushort ps[4][16][PITCH];   // per-wave P tile:    [q][k]

    const int bid  = blockIdx.x;
    const int qt   = bid & 15;            // q-tile index within bh
    const int bh   = bid >> 4;            // batch*head
    const int bb   = bh >> 3;             // batch
    const int tid  = threadIdx.x;
    const int wid  = tid >> 6;
    const int lane = tid & 63;
    const int i16  = lane & 15;           // MFMA n / A-m index
    const int g4   = lane >> 4;           // MFMA k-group; C/D row group

    const float* Qb = Q + (size_t)bh * (HD * SEQ);
    const float* Kb = K + (size_t)bh * (HD * SEQ);
    const float* Vb = V + (size_t)bh * (HD * SEQ);
    const float* Mb = M + (size_t)bb * (SEQ * SEQ);
    float*       Ob = O + (size_t)bh * (HD * SEQ);

    const int q0 = qt * QB;

    // ---- stage Q tile transposed: qs[q_local][d] (global is Q[d][q], coalesced along q) ----
    #pragma unroll
    for (int it = 0; it < 4; ++it) {
        int dd = (tid >> 4) + 16 * it;          // 0..63
        int qq = (tid & 15) * 4;                // 0..60
        float4 f = *(const float4*)(Qb + (size_t)dd * SEQ + q0 + qq);
        qs[qq + 0][dd] = f2bf(f.x);
        qs[qq + 1][dd] = f2bf(f.y);
        qs[qq + 2][dd] = f2bf(f.z);
        qs[qq + 3][dd] = f2bf(f.w);
    }
    __syncthreads();

    // ---- per-wave Q A-fragments (row m = i16 -> q = wid*16+i16; k-slot (g,j) -> d = 32cc+8g+j) ----
    F8 aq[2];
    {
        int qr = wid * 16 + i16;
        #pragma unroll
        for (int cc = 0; cc < 2; ++cc) {
            const uint2* p = (const uint2*)&qs[qr][cc * 32 + 8 * g4];
            aq[cc].u2[0] = p[0];
            aq[cc].u2[1] = p[1];
        }
    }

    floatx4 oacc[4];
    float mrun[4], lrun[4];
    #pragma unroll
    for (int r = 0; r < 4; ++r) { mrun[r] = -3e38f; lrun[r] = 0.0f; }
    #pragma unroll
    for (int t = 0; t < 4; ++t) oacc[t] = (floatx4){0.f, 0.f, 0.f, 0.f};

    const float scale = 0.125f;   // 64^-0.5

    for (int kt = 0; kt < SEQ / KB; ++kt) {
        __syncthreads();   // previous tile fully consumed
        // ---- stage K (transpose -> [k][d]) and V (native -> [d][k]) ----
        #pragma unroll
        for (int it = 0; it < 4; ++it) {
            int slot = tid + 256 * it;          // 0..1023
            int dd   = slot >> 4;               // 0..63
            int kk4  = (slot & 15) * 4;         // 0..60
            float4 fk = *(const float4*)(Kb + (size_t)dd * SEQ + kt * KB + kk4);
            ks[kk4 + 0][dd] = f2bf(fk.x);
            ks[kk4 + 1][dd] = f2bf(fk.y);
            ks[kk4 + 2][dd] = f2bf(fk.z);
            ks[kk4 + 3][dd] = f2bf(fk.w);
            float4 fv = *(const float4*)(Vb + (size_t)dd * SEQ + kt * KB + kk4);
            ushort4 pv;
            pv.x = f2bf(fv.x); pv.y = f2bf(fv.y); pv.z = f2bf(fv.z); pv.w = f2bf(fv.w);
            *(ushort4*)&vs[dd][kk4] = pv;       // 8B aligned (kk4 mult of 4, row 136B)
        }
        __syncthreads();

        // ---- mask prefetch (issue early; mostly L2/L3 hits) ----
        float mv[4][4];   // [nt][r]
        {
            const float* mp = Mb + (size_t)(q0 + wid * 16 + 4 * g4) * SEQ + kt * KB + i16;
            #pragma unroll
            for (int r = 0; r < 4; ++r)
                #pragma unroll
                for (int nt = 0; nt < 4; ++nt)
                    mv[nt][r] = mp[r * SEQ + nt * 16];
        }

        // ---- QK^T: S[q][k], q rows from A(Q), k cols from B(K) ----
        floatx4 sacc[4];
        #pragma unroll
        for (int nt = 0; nt < 4; ++nt) sacc[nt] = (floatx4){0.f, 0.f, 0.f, 0.f};
        #pragma unroll
        for (int cc = 0; cc < 2; ++cc) {
            #pragma unroll
            for (int nt = 0; nt < 4; ++nt) {
                F8 bk;
                const uint2* p = (const uint2*)&ks[nt * 16 + i16][cc * 32 + 8 * g4];
                bk.u2[0] = p[0]; bk.u2[1] = p[1];
                sacc[nt] = __builtin_amdgcn_mfma_f32_16x16x32_bf16(aq[cc].s8, bk.s8, sacc[nt], 0, 0, 0);
            }
        }

        // ---- masked online softmax (C/D layout: col = i16, row = 4*g4 + r) ----
        float sm[4][4];
        #pragma unroll
        for (int nt = 0; nt < 4; ++nt)
            #pragma unroll
            for (int r = 0; r < 4; ++r)
                sm[nt][r] = (mv[nt][r] > -1.0f) ? sacc[nt][r] * scale : -3e38f;

        float ef[4];
        float pf[4][4];
        #pragma unroll
        for (int r = 0; r < 4; ++r) {
            float tmax = fmaxf(fmaxf(sm[0][r], sm[1][r]), fmaxf(sm[2][r], sm[3][r]));
            #pragma unroll
            for (int off = 1; off < 16; off <<= 1)
                tmax = fmaxf(tmax, __shfl_xor(tmax, off));
            float mnew = fmaxf(mrun[r], tmax);
            ef[r] = __expf(mrun[r] - mnew);        // ==0 when mrun=-3e38 and mnew finite
            float ls = 0.0f;
            #pragma unroll
            for (int nt = 0; nt < 4; ++nt) {
                float p = __expf(sm[nt][r] - mnew); // masked -> exp(-3e38) == 0
                pf[nt][r] = p;
                ls += p;
            }
            #pragma unroll
            for (int off = 1; off < 16; off <<= 1)
                ls += __shfl_xor(ls, off);
            lrun[r] = lrun[r] * ef[r] + ls;
            mrun[r] = mnew;
        }
        #pragma unroll
        for (int t = 0; t < 4; ++t)
            #pragma unroll
            for (int r = 0; r < 4; ++r)
                oacc[t][r] *= ef[r];

        // ---- P -> per-wave LDS (bf16), then PV MFMA ----
        #pragma unroll
        for (int nt = 0; nt < 4; ++nt)
            #pragma unroll
            for (int r = 0; r < 4; ++r)
                ps[wid][4 * g4 + r][nt * 16 + i16] = f2bf(pf[nt][r]);

        #pragma unroll
        for (int cc = 0; cc < 2; ++cc) {
            F8 ap;   // A: m = i16 (q-row), k-slot -> key = 32cc+8g+j
            const uint2* pp = (const uint2*)&ps[wid][i16][cc * 32 + 8 * g4];
            ap.u2[0] = pp[0]; ap.u2[1] = pp[1];
            #pragma unroll
            for (int dt = 0; dt < 4; ++dt) {
                F8 bv;  // B: n = d = 16dt+i16, k-slot -> key = 32cc+8g+j ; vs is [d][k]
                const uint2* pv = (const uint2*)&vs[dt * 16 + i16][cc * 32 + 8 * g4];
                bv.u2[0] = pv[0]; bv.u2[1] = pv[1];
                oacc[dt] = __builtin_amdgcn_mfma_f32_16x16x32_bf16(ap.s8, bv.s8, oacc[dt], 0, 0, 0);
            }
        }
    }

    // ---- epilogue: out[d][q] = oacc/lsum ; rows r are consecutive q -> float4 store ----
    #pragma unroll
    for (int dt = 0; dt < 4; ++dt) {
        float4 o;
        o.x = oacc[dt][0] / lrun[0];
        o.y = oacc[dt][1] / lrun[1];
        o.z = oacc[dt][2] / lrun[2];
        o.w = oacc[dt][3] / lrun[3];
        *(float4*)(Ob + (size_t)(dt * 16 + i16) * SEQ + q0 + wid * 16 + 4 * g4) = o;
    }
}

extern "C" void kernel_launch(void* const* d_in, const int* in_sizes, int n_in,
                              void* d_out, int out_size, void* d_ws, size_t ws_size,
                              hipStream_t stream) {
    const float* q = (const float*)d_in[0];
    const float* k = (const float*)d_in[1];
    const float* v = (const float*)d_in[2];
    const float* m = (const float*)d_in[3];
    float* out = (float*)d_out;
    // 64 bh * 16 q-tiles = 1024 blocks, 256 threads (4 waves)
    mha_fwd_kernel<<<dim3(1024), dim3(256), 0, stream>>>(q, k, v, m, out);
}

// Round 2
// 158.635 us; speedup vs baseline: 1.2277x; 1.2277x over previous
//
#include <hip/hip_runtime.h>

// MHA forward, MI355X gfx950. b=8, heads=8 -> bh=64; S=1024; d=64. fp32 in/out.
// Round 2: prepass (bf16 transpose + mask bitpack) + swapped-QK flash main kernel
// with global_load_lds staging (pre-swizzled source), double-buffered LDS,
// in-register P exchange (cvt_pk_bf16 + bpermute). Fallback to round-1 kernel
// if ws_size too small.

#define SEQ   1024
#define HD    64
#define QB    64
#define KB    64
#define NT    16      // SEQ/KB

typedef __attribute__((ext_vector_type(8))) short short8;     // 8 bf16
typedef __attribute__((ext_vector_type(8))) unsigned short us8;
typedef __attribute__((ext_vector_type(4))) float floatx4;

union F8 { short8 s8; unsigned u[4]; unsigned short h[8]; };

__device__ __forceinline__ unsigned short f2bf(float f) {
    union { float f; unsigned u; } cv; cv.f = f;
    unsigned u = cv.u + 0x7FFFu + ((cv.u >> 16) & 1u);
    return (unsigned short)(u >> 16);
}

__device__ __forceinline__ unsigned cvt_pk_bf16(float lo, float hi) {
    unsigned r;
    asm("v_cvt_pk_bf16_f32 %0, %1, %2" : "=v"(r) : "v"(lo), "v"(hi));
    return r;
}

__device__ __forceinline__ void gload16(void* lds, const void* g) {
    __builtin_amdgcn_global_load_lds((const __attribute__((address_space(1))) unsigned*)g,
                                     (__attribute__((address_space(3))) unsigned*)lds,
                                     16, 0, 0);
}

// ============================ prepass ============================
// blocks [0,1024): Q transpose+convert (scale 0.125 folded)
// blocks [1024,2048): K transpose+convert
// blocks [2048,4096): V convert (native layout)
// blocks [4096,8192): mask -> bitmask (bit=1 means keep, mask value == 0)
__global__ __launch_bounds__(256)
void mha_prep(const float* __restrict__ Q, const float* __restrict__ K,
              const float* __restrict__ V, const float* __restrict__ M,
              unsigned short* __restrict__ QT, unsigned short* __restrict__ KT,
              unsigned short* __restrict__ VT, unsigned* __restrict__ BM)
{
    const int bx = blockIdx.x, tid = threadIdx.x;
    __shared__ float tile[64][65];

    if (bx < 2048) {
        const bool isQ = bx < 1024;
        const int id = isQ ? bx : bx - 1024;
        const int bh = id >> 4, st = id & 15;
        const float* src = (isQ ? Q : K) + (size_t)bh * HD * SEQ;
        unsigned short* dst = (isQ ? QT : KT) + (size_t)bh * SEQ * HD;
        const float scale = isQ ? 0.125f : 1.0f;

        const int d = tid >> 2, c = tid & 3;
        #pragma unroll
        for (int i = 0; i < 4; ++i) {
            int col = c * 4 + 16 * i;
            float4 f = *(const float4*)(src + (size_t)d * SEQ + st * 64 + col);
            tile[d][col + 0] = f.x * scale;
            tile[d][col + 1] = f.y * scale;
            tile[d][col + 2] = f.z * scale;
            tile[d][col + 3] = f.w * scale;
        }
        __syncthreads();
        const int s = tid >> 2, c4 = tid & 3;
        us8 o0, o1;
        #pragma unroll
        for (int dd = 0; dd < 8; ++dd)  o0[dd] = f2bf(tile[16 * c4 + dd][s]);
        #pragma unroll
        for (int dd = 8; dd < 16; ++dd) o1[dd - 8] = f2bf(tile[16 * c4 + dd][s]);
        unsigned short* drow = dst + (size_t)(st * 64 + s) * 64 + c4 * 16;
        *(us8*)(drow)     = o0;
        *(us8*)(drow + 8) = o1;
    } else if (bx < 4096) {
        size_t base = ((size_t)(bx - 2048) * 256 + tid) * 8;
        float4 f0 = *(const float4*)(V + base);
        float4 f1 = *(const float4*)(V + base + 4);
        us8 o;
        o[0] = f2bf(f0.x); o[1] = f2bf(f0.y); o[2] = f2bf(f0.z); o[3] = f2bf(f0.w);
        o[4] = f2bf(f1.x); o[5] = f2bf(f1.y); o[6] = f2bf(f1.z); o[7] = f2bf(f1.w);
        *(us8*)(VT + base) = o;
    } else {
        size_t base = ((size_t)(bx - 4096) * 256 + tid) * 8;
        float4 f0 = *(const float4*)(M + base);
        float4 f1 = *(const float4*)(M + base + 4);
        unsigned byte =
            ((unsigned)(f0.x > -1.f))      | ((unsigned)(f0.y > -1.f) << 1) |
            ((unsigned)(f0.z > -1.f) << 2) | ((unsigned)(f0.w > -1.f) << 3) |
            ((unsigned)(f1.x > -1.f) << 4) | ((unsigned)(f1.y > -1.f) << 5) |
            ((unsigned)(f1.z > -1.f) << 6) | ((unsigned)(f1.w > -1.f) << 7);
        ((unsigned char*)BM)[base >> 3] = (unsigned char)byte;
    }
}

// ============================ main kernel ============================
__global__ __launch_bounds__(256, 4)
void mha_main(const unsigned short* __restrict__ QT, const unsigned short* __restrict__ KT,
              const unsigned short* __restrict__ VT, const unsigned* __restrict__ BM,
              float* __restrict__ O)
{
    __shared__ __align__(16) unsigned short ks[2][KB * HD];  // [row=key][d], swizzled
    __shared__ __align__(16) unsigned short vs[2][HD * KB];  // [row=d][key], swizzled

    const int bid = blockIdx.x;
    const int qt = bid & 15, bh = bid >> 4, b = bh >> 3;
    const int tid = threadIdx.x, w = tid >> 6, lane = tid & 63;
    const int i16 = lane & 15, g4 = lane >> 4;
    const int q0 = qt * QB;
    const int myq = q0 + w * 16 + i16;

    const char* QTb = (const char*)(QT + (size_t)bh * SEQ * HD);
    const char* KTb = (const char*)(KT + (size_t)bh * SEQ * HD);
    const char* VTb = (const char*)(VT + (size_t)bh * HD * SEQ);
    const unsigned* BMq = BM + ((size_t)b * SEQ + myq) * (SEQ / 32);
    float* Ob = O + (size_t)bh * HD * SEQ;

    // per-lane staging source swizzle: LDS[row][x] = G[row][x ^ ((row&7)<<4)]
    const int srow  = lane >> 3;                       // 0..7
    const int sbyte = ((lane & 7) * 16) ^ (srow << 4); // byte-in-row, pre-swizzled

    // ---- prologue: stage Q tile -> ks[1]; K/V tile 0 -> buf 0 ----
    #pragma unroll
    for (int i = 0; i < 2; ++i) {
        int row = w * 16 + i * 8 + srow;
        char* ldst = (char*)&ks[1][0] + w * 2048 + i * 1024;
        gload16(ldst, QTb + (size_t)(q0 + row) * 128 + sbyte);
        char* kdst = (char*)&ks[0][0] + w * 2048 + i * 1024;
        gload16(kdst, KTb + (size_t)row * 128 + sbyte);
        char* vdst = (char*)&vs[0][0] + w * 2048 + i * 1024;
        gload16(vdst, VTb + (size_t)row * 2048 + sbyte);
    }
    __syncthreads();

    // Q B-fragments: lane n=q=i16 (row w*16+i16), k-slot d = 32cc+8g4+j
    F8 qf[2];
    {
        int row = w * 16 + i16;
        #pragma unroll
        for (int cc = 0; cc < 2; ++cc) {
            int off = row * 64 + (((cc << 5) + (g4 << 3)) ^ ((row & 7) << 3));
            qf[cc].s8 = *(const short8*)(&ks[1][0] + off);
        }
    }
    __syncthreads();   // everyone done with ks[1] before tile0 prefetch reuses it

    floatx4 oacc[4];
    #pragma unroll
    for (int t = 0; t < 4; ++t) oacc[t] = (floatx4){0.f, 0.f, 0.f, 0.f};
    float mrun = -3e38f, lrun = 0.0f;

    int cur = 0;
    for (int kt = 0; kt < NT; ++kt) {
        // ---- prefetch next K/V tile into buf^1 ----
        if (kt + 1 < NT) {
            int nxt = cur ^ 1;
            #pragma unroll
            for (int i = 0; i < 2; ++i) {
                int row = w * 16 + i * 8 + srow;
                char* kdst = (char*)&ks[nxt][0] + w * 2048 + i * 1024;
                gload16(kdst, KTb + (size_t)(kt + 1) * 8192 + (size_t)row * 128 + sbyte);
                char* vdst = (char*)&vs[nxt][0] + w * 2048 + i * 1024;
                gload16(vdst, VTb + (size_t)row * 2048 + (size_t)(kt + 1) * 128 + sbyte);
            }
        }
        // ---- mask bits for my q-row, this key tile ----
        uint2 mw = *(const uint2*)(BMq + kt * 2);

        // ---- QK^T (swapped): sacc[nt] = S^T[key][q], col=q=i16, row=key-sub 4g4+r ----
        floatx4 sacc[4];
        #pragma unroll
        for (int nt = 0; nt < 4; ++nt) sacc[nt] = (floatx4){0.f, 0.f, 0.f, 0.f};
        #pragma unroll
        for (int nt = 0; nt < 4; ++nt) {
            int row = nt * 16 + i16;
            #pragma unroll
            for (int cc = 0; cc < 2; ++cc) {
                int off = row * 64 + (((cc << 5) + (g4 << 3)) ^ ((row & 7) << 3));
                F8 kf; kf.s8 = *(const short8*)(&ks[cur][0] + off);
                sacc[nt] = __builtin_amdgcn_mfma_f32_16x16x32_bf16(kf.s8, qf[cc].s8, sacc[nt], 0, 0, 0);
            }
        }

        // ---- masked online softmax: lane owns one q-row, 16 key-values ----
        float sm[4][4];
        #pragma unroll
        for (int nt = 0; nt < 4; ++nt) {
            unsigned wm = (nt < 2) ? mw.x : mw.y;
            #pragma unroll
            for (int r = 0; r < 4; ++r) {
                int bit = ((nt & 1) << 4) + (g4 << 2) + r;
                sm[nt][r] = ((wm >> bit) & 1u) ? sacc[nt][r] : -3e38f;
            }
        }
        float tm = sm[0][0];
        #pragma unroll
        for (int nt = 0; nt < 4; ++nt)
            #pragma unroll
            for (int r = 0; r < 4; ++r)
                tm = fmaxf(tm, sm[nt][r]);
        tm = fmaxf(tm, __shfl_xor(tm, 16));
        tm = fmaxf(tm, __shfl_xor(tm, 32));
        float mnew = fmaxf(mrun, tm);
        float ef = __expf(mrun - mnew);
        float p[4][4];
        float ls = 0.0f;
        #pragma unroll
        for (int nt = 0; nt < 4; ++nt)
            #pragma unroll
            for (int r = 0; r < 4; ++r) {
                float pv = __expf(sm[nt][r] - mnew);   // masked -> exp(-huge) == 0
                p[nt][r] = pv;
                ls += pv;
            }
        ls += __shfl_xor(ls, 16);
        ls += __shfl_xor(ls, 32);
        lrun = lrun * ef + ls;
        mrun = mnew;
        #pragma unroll
        for (int t = 0; t < 4; ++t)
            #pragma unroll
            for (int r = 0; r < 4; ++r)
                oacc[t][r] *= ef;

        // ---- P exchange: build PV B-fragment (lane n=q=i16, k=key=32cc+8g4+j) ----
        unsigned W[4][2];
        #pragma unroll
        for (int nt = 0; nt < 4; ++nt) {
            W[nt][0] = cvt_pk_bf16(p[nt][0], p[nt][1]);
            W[nt][1] = cvt_pk_bf16(p[nt][2], p[nt][3]);
        }
        const int srcA = i16 + ((g4 & 1) << 5);   // source lane group 2*(g4&1)
        const int srcB = srcA + 16;               // source lane group 2*(g4&1)+1
        const bool hi = (g4 >> 1) != 0;           // pick nt' = 2cc + (g4>>1)
        F8 pb[2];
        #pragma unroll
        for (int cc = 0; cc < 2; ++cc) {
            unsigned a0 = (unsigned)__shfl((int)W[2 * cc][0],     srcA);
            unsigned b0 = (unsigned)__shfl((int)W[2 * cc + 1][0], srcA);
            unsigned a1 = (unsigned)__shfl((int)W[2 * cc][1],     srcA);
            unsigned b1 = (unsigned)__shfl((int)W[2 * cc + 1][1], srcA);
            unsigned a2 = (unsigned)__shfl((int)W[2 * cc][0],     srcB);
            unsigned b2 = (unsigned)__shfl((int)W[2 * cc + 1][0], srcB);
            unsigned a3 = (unsigned)__shfl((int)W[2 * cc][1],     srcB);
            unsigned b3 = (unsigned)__shfl((int)W[2 * cc + 1][1], srcB);
            pb[cc].u[0] = hi ? b0 : a0;
            pb[cc].u[1] = hi ? b1 : a1;
            pb[cc].u[2] = hi ? b2 : a2;
            pb[cc].u[3] = hi ? b3 : a3;
        }

        // ---- PV: oacc[dt] = O[d][q] sub-tile, A=V(m=d), B=P^T(n=q) ----
        #pragma unroll
        for (int cc = 0; cc < 2; ++cc) {
            #pragma unroll
            for (int dt = 0; dt < 4; ++dt) {
                int row = dt * 16 + i16;
                int off = row * 64 + (((cc << 5) + (g4 << 3)) ^ ((row & 7) << 3));
                F8 vf; vf.s8 = *(const short8*)(&vs[cur][0] + off);
                oacc[dt] = __builtin_amdgcn_mfma_f32_16x16x32_bf16(vf.s8, pb[cc].s8, oacc[dt], 0, 0, 0);
            }
        }
        __syncthreads();
        cur ^= 1;
    }

    // ---- epilogue: O[d][q], d = dt*16 + 4*g4 + r, q = myq ----
    float inv = 1.0f / lrun;
    #pragma unroll
    for (int dt = 0; dt < 4; ++dt)
        #pragma unroll
        for (int r = 0; r < 4; ++r)
            Ob[(size_t)(dt * 16 + 4 * g4 + r) * SEQ + myq] = oacc[dt][r] * inv;
}

// ============================ fallback (round-1, known-good) ============================
#define PITCH 68
__global__ __launch_bounds__(256)
void mha_fallback(const float* __restrict__ Q, const float* __restrict__ K,
                  const float* __restrict__ V, const float* __restrict__ M,
                  float* __restrict__ O)
{
    __shared__ unsigned short ksl[KB][PITCH];
    __shared__ unsigned short vsl[HD][PITCH];
    __shared__ unsigned short qsl[QB][PITCH];
    __shared__ unsigned short psl[4][16][PITCH];

    const int bid  = blockIdx.x;
    const int qt   = bid & 15;
    const int bh   = bid >> 4;
    const int bb   = bh >> 3;
    const int tid  = threadIdx.x;
    const int wid  = tid >> 6;
    const int lane = tid & 63;
    const int i16  = lane & 15;
    const int g4   = lane >> 4;

    const float* Qb = Q + (size_t)bh * (HD * SEQ);
    const float* Kb = K + (size_t)bh * (HD * SEQ);
    const float* Vb = V + (size_t)bh * (HD * SEQ);
    const float* Mb = M + (size_t)bb * (SEQ * SEQ);
    float*       Ob = O + (size_t)bh * (HD * SEQ);

    const int q0 = qt * QB;

    #pragma unroll
    for (int it = 0; it < 4; ++it) {
        int dd = (tid >> 4) + 16 * it;
        int qq = (tid & 15) * 4;
        float4 f = *(const float4*)(Qb + (size_t)dd * SEQ + q0 + qq);
        qsl[qq + 0][dd] = f2bf(f.x);
        qsl[qq + 1][dd] = f2bf(f.y);
        qsl[qq + 2][dd] = f2bf(f.z);
        qsl[qq + 3][dd] = f2bf(f.w);
    }
    __syncthreads();

    F8 aq[2];
    {
        int qr = wid * 16 + i16;
        #pragma unroll
        for (int cc = 0; cc < 2; ++cc) {
            const uint2* pp = (const uint2*)&qsl[qr][cc * 32 + 8 * g4];
            aq[cc].u[0] = pp[0].x; aq[cc].u[1] = pp[0].y;
            aq[cc].u[2] = pp[1].x; aq[cc].u[3] = pp[1].y;
        }
    }

    floatx4 oacc[4];
    float mrun[4], lrun[4];
    #pragma unroll
    for (int r = 0; r < 4; ++r) { mrun[r] = -3e38f; lrun[r] = 0.0f; }
    #pragma unroll
    for (int t = 0; t < 4; ++t) oacc[t] = (floatx4){0.f, 0.f, 0.f, 0.f};

    const float scale = 0.125f;

    for (int kt = 0; kt < SEQ / KB; ++kt) {
        __syncthreads();
        #pragma unroll
        for (int it = 0; it < 4; ++it) {
            int slot = tid + 256 * it;
            int dd   = slot >> 4;
            int kk4  = (slot & 15) * 4;
            float4 fk = *(const float4*)(Kb + (size_t)dd * SEQ + kt * KB + kk4);
            ksl[kk4 + 0][dd] = f2bf(fk.x);
            ksl[kk4 + 1][dd] = f2bf(fk.y);
            ksl[kk4 + 2][dd] = f2bf(fk.z);
            ksl[kk4 + 3][dd] = f2bf(fk.w);
            float4 fv = *(const float4*)(Vb + (size_t)dd * SEQ + kt * KB + kk4);
            ushort4 pv;
            pv.x = f2bf(fv.x); pv.y = f2bf(fv.y); pv.z = f2bf(fv.z); pv.w = f2bf(fv.w);
            *(ushort4*)&vsl[dd][kk4] = pv;
        }
        __syncthreads();

        float mv[4][4];
        {
            const float* mp = Mb + (size_t)(q0 + wid * 16 + 4 * g4) * SEQ + kt * KB + i16;
            #pragma unroll
            for (int r = 0; r < 4; ++r)
                #pragma unroll
                for (int nt = 0; nt < 4; ++nt)
                    mv[nt][r] = mp[r * SEQ + nt * 16];
        }

        floatx4 sacc[4];
        #pragma unroll
        for (int nt = 0; nt < 4; ++nt) sacc[nt] = (floatx4){0.f, 0.f, 0.f, 0.f};
        #pragma unroll
        for (int cc = 0; cc < 2; ++cc) {
            #pragma unroll
            for (int nt = 0; nt < 4; ++nt) {
                F8 bk;
                const uint2* pp = (const uint2*)&ksl[nt * 16 + i16][cc * 32 + 8 * g4];
                bk.u[0] = pp[0].x; bk.u[1] = pp[0].y; bk.u[2] = pp[1].x; bk.u[3] = pp[1].y;
                sacc[nt] = __builtin_amdgcn_mfma_f32_16x16x32_bf16(aq[cc].s8, bk.s8, sacc[nt], 0, 0, 0);
            }
        }

        float sm[4][4];
        #pragma unroll
        for (int nt = 0; nt < 4; ++nt)
            #pragma unroll
            for (int r = 0; r < 4; ++r)
                sm[nt][r] = (mv[nt][r] > -1.0f) ? sacc[nt][r] * scale : -3e38f;

        float ef[4];
        float pf[4][4];
        #pragma unroll
        for (int r = 0; r < 4; ++r) {
            float tmax = fmaxf(fmaxf(sm[0][r], sm[1][r]), fmaxf(sm[2][r], sm[3][r]));
            #pragma unroll
            for (int off = 1; off < 16; off <<= 1)
                tmax = fmaxf(tmax, __shfl_xor(tmax, off));
            float mnew = fmaxf(mrun[r], tmax);
            ef[r] = __expf(mrun[r] - mnew);
            float lsl = 0.0f;
            #pragma unroll
            for (int nt = 0; nt < 4; ++nt) {
                float pv = __expf(sm[nt][r] - mnew);
                pf[nt][r] = pv;
                lsl += pv;
            }
            #pragma unroll
            for (int off = 1; off < 16; off <<= 1)
                lsl += __shfl_xor(lsl, off);
            lrun[r] = lrun[r] * ef[r] + lsl;
            mrun[r] = mnew;
        }
        #pragma unroll
        for (int t = 0; t < 4; ++t)
            #pragma unroll
            for (int r = 0; r < 4; ++r)
                oacc[t][r] *= ef[r];

        #pragma unroll
        for (int nt = 0; nt < 4; ++nt)
            #pragma unroll
            for (int r = 0; r < 4; ++r)
                psl[wid][4 * g4 + r][nt * 16 + i16] = f2bf(pf[nt][r]);

        #pragma unroll
        for (int cc = 0; cc < 2; ++cc) {
            F8 ap;
            const uint2* pp = (const uint2*)&psl[wid][i16][cc * 32 + 8 * g4];
            ap.u[0] = pp[0].x; ap.u[1] = pp[0].y; ap.u[2] = pp[1].x; ap.u[3] = pp[1].y;
            #pragma unroll
            for (int dt = 0; dt < 4; ++dt) {
                F8 bv;
                const uint2* pv = (const uint2*)&vsl[dt * 16 + i16][cc * 32 + 8 * g4];
                bv.u[0] = pv[0].x; bv.u[1] = pv[0].y; bv.u[2] = pv[1].x; bv.u[3] = pv[1].y;
                oacc[dt] = __builtin_amdgcn_mfma_f32_16x16x32_bf16(ap.s8, bv.s8, oacc[dt], 0, 0, 0);
            }
        }
    }

    #pragma unroll
    for (int dt = 0; dt < 4; ++dt) {
        float4 o;
        o.x = oacc[dt][0] / lrun[0];
        o.y = oacc[dt][1] / lrun[1];
        o.z = oacc[dt][2] / lrun[2];
        o.w = oacc[dt][3] / lrun[3];
        *(float4*)(Ob + (size_t)(dt * 16 + i16) * SEQ + q0 + wid * 16 + 4 * g4) = o;
    }
}

extern "C" void kernel_launch(void* const* d_in, const int* in_sizes, int n_in,
                              void* d_out, int out_size, void* d_ws, size_t ws_size,
                              hipStream_t stream) {
    const float* q = (const float*)d_in[0];
    const float* k = (const float*)d_in[1];
    const float* v = (const float*)d_in[2];
    const float* m = (const float*)d_in[3];
    float* out = (float*)d_out;

    const size_t SZ_QT = (size_t)64 * SEQ * HD * 2;   // 8 MB
    const size_t NEED  = 3 * SZ_QT + (size_t)8 * SEQ * (SEQ / 8);  // 25 MB

    if (ws_size >= NEED && d_ws != nullptr) {
        unsigned short* QT = (unsigned short*)d_ws;
        unsigned short* KT = (unsigned short*)((char*)d_ws + SZ_QT);
        unsigned short* VT = (unsigned short*)((char*)d_ws + 2 * SZ_QT);
        unsigned*       BM = (unsigned*)((char*)d_ws + 3 * SZ_QT);
        mha_prep<<<dim3(8192), dim3(256), 0, stream>>>(q, k, v, m, QT, KT, VT, BM);
        mha_main<<<dim3(1024), dim3(256), 0, stream>>>(QT, KT, VT, BM, out);
    } else {
        mha_fallback<<<dim3(1024), dim3(256), 0, stream>>>(q, k, v, m, out);
    }
}

// Round 5
// 154.265 us; speedup vs baseline: 1.2624x; 1.0283x over previous
//
#include <hip/hip_runtime.h>

// MHA forward, MI355X gfx950. b=8, heads=8 -> bh=64; S=1024; d=64. fp32 in/out.
// Round 5 = round 4 resubmit (infra failures, never ran).
// 32x32x16 MFMA, QB=128 per block (4 waves x 32q), exp2-domain softmax,
// defer-max, mask-after-exp, shfl_xor(32) P-exchange, XCD-aware block swizzle.
// Prep: LDS transpose (b128 writes, coalesced stores) + V convert + mask bitpack.
// Scale 0.125*log2(e) folded into Q prep.

#define SEQ 1024
#define HD  64

typedef __attribute__((ext_vector_type(8)))  short short8;
typedef __attribute__((ext_vector_type(8)))  unsigned short us8;
typedef __attribute__((ext_vector_type(16))) float f32x16;

union F8 { short8 s8; unsigned u[4]; };

__device__ __forceinline__ unsigned short f2bf(float f) {
    union { float f; unsigned u; } cv; cv.f = f;
    unsigned u = cv.u + 0x7FFFu + ((cv.u >> 16) & 1u);   // RNE
    return (unsigned short)(u >> 16);
}
__device__ __forceinline__ unsigned cvt_pk_bf16(float lo, float hi) {
    unsigned r;
    asm("v_cvt_pk_bf16_f32 %0, %1, %2" : "=v"(r) : "v"(lo), "v"(hi));
    return r;
}
__device__ __forceinline__ float ex2(float x) {   // 2^x, single v_exp_f32
    float r;
    asm("v_exp_f32 %0, %1" : "=v"(r) : "v"(x));
    return r;
}
__device__ __forceinline__ void gload16(void* lds, const void* g) {
    __builtin_amdgcn_global_load_lds((const __attribute__((address_space(1))) unsigned*)g,
                                     (__attribute__((address_space(3))) unsigned*)lds,
                                     16, 0, 0);
}

// ============================ prepass ============================
// blocks [0,1024): Q -> QT[q][d] bf16 (scale 0.125*log2e folded)
// blocks [1024,2048): K -> KT[k][d] bf16
// blocks [2048,4096): V -> VT[d][s] bf16 (native layout)
// blocks [4096,8192): mask -> bitmask (bit=1 keep)
__global__ __launch_bounds__(256)
void mha_prep(const float* __restrict__ Q, const float* __restrict__ K,
              const float* __restrict__ V, const float* __restrict__ M,
              unsigned short* __restrict__ QT, unsigned short* __restrict__ KT,
              unsigned short* __restrict__ VT, unsigned char* __restrict__ BM)
{
    __shared__ float tile[64][68];   // pitch 68: 16B-aligned rows for b128 writes
    const int bx = blockIdx.x, tid = threadIdx.x;

    if (bx < 2048) {
        const bool isQ = bx < 1024;
        const int id = isQ ? bx : bx - 1024;
        const int bh = id >> 4, st = id & 15;
        const float* src = (isQ ? Q : K) + (size_t)bh * HD * SEQ;
        unsigned short* dst = (isQ ? QT : KT) + (size_t)bh * SEQ * HD;
        const float scale = isQ ? 0.125f * 1.4426950408889634f : 1.0f;
        const int s0 = st * 64;

        const int d = tid >> 2, sc = tid & 3;
        #pragma unroll
        for (int i = 0; i < 4; ++i) {
            int col = sc * 4 + i * 16;
            float4 f = *(const float4*)(src + (size_t)d * SEQ + s0 + col);
            f.x *= scale; f.y *= scale; f.z *= scale; f.w *= scale;
            *(float4*)&tile[d][col] = f;
        }
        __syncthreads();
        const int grp = tid >> 3, a = tid & 7;
        #pragma unroll
        for (int j = 0; j < 2; ++j) {
            int s = j * 32 + grp;     // output q-row
            int d0 = a * 8;
            us8 o;
            #pragma unroll
            for (int dd = 0; dd < 8; ++dd) o[dd] = f2bf(tile[d0 + dd][s]);
            *(us8*)(dst + (size_t)(s0 + s) * HD + d0) = o;   // wave writes 8 rows x 128B
        }
    } else if (bx < 4096) {
        size_t base = ((size_t)(bx - 2048) * 256 + tid) * 8;
        float4 f0 = *(const float4*)(V + base);
        float4 f1 = *(const float4*)(V + base + 4);
        us8 o;
        o[0] = f2bf(f0.x); o[1] = f2bf(f0.y); o[2] = f2bf(f0.z); o[3] = f2bf(f0.w);
        o[4] = f2bf(f1.x); o[5] = f2bf(f1.y); o[6] = f2bf(f1.z); o[7] = f2bf(f1.w);
        *(us8*)(VT + base) = o;
    } else {
        size_t base = ((size_t)(bx - 4096) * 256 + tid) * 8;
        float4 f0 = *(const float4*)(M + base);
        float4 f1 = *(const float4*)(M + base + 4);
        unsigned byte =
            (unsigned)(f0.x > -1.f)        | ((unsigned)(f0.y > -1.f) << 1) |
            ((unsigned)(f0.z > -1.f) << 2) | ((unsigned)(f0.w > -1.f) << 3) |
            ((unsigned)(f1.x > -1.f) << 4) | ((unsigned)(f1.y > -1.f) << 5) |
            ((unsigned)(f1.z > -1.f) << 6) | ((unsigned)(f1.w > -1.f) << 7);
        BM[base >> 3] = (unsigned char)byte;
    }
}

// ============================ main kernel ============================
// Grid 512: bid -> xcd = bid&7; bh = (bid&7)*8 + ((bid>>3)&7) (whole batch per XCD);
// qt = bid>>6 (8 q-tiles of 128). 4 waves, wave w owns q = q0 + w*32 + (lane&31).
// Swapped QK^T: mfma(A=K, B=Q) -> S^T, lane col = q. PV: mfma(A=V, B=P^T) -> O^T.
__global__ __launch_bounds__(256)
void mha_main(const unsigned short* __restrict__ QT, const unsigned short* __restrict__ KT,
              const unsigned short* __restrict__ VT, const unsigned* __restrict__ BM,
              float* __restrict__ O)
{
    __shared__ __align__(16) unsigned short kbuf[2][4096];   // 8KB: [key][d] swizzled
    __shared__ __align__(16) unsigned short vbuf[2][4096];   // 8KB: [d][key] swizzled

    const int bid = blockIdx.x;
    const int qt = bid >> 6;
    const int bh = ((bid & 7) << 3) | ((bid >> 3) & 7);
    const int b  = bh >> 3;
    const int tid = threadIdx.x, w = tid >> 6, lane = tid & 63;
    const int l31 = lane & 31, g = lane >> 5;
    const int q0 = qt * 128;
    const int myq = q0 + w * 32 + l31;

    const unsigned short* QTb = QT + (size_t)bh * SEQ * HD;
    const unsigned short* KTb = KT + (size_t)bh * SEQ * HD;
    const unsigned short* VTb = VT + (size_t)bh * HD * SEQ;
    const unsigned* BMq = BM + ((size_t)b * SEQ + myq) * (SEQ / 32);   // 32 uints per q-row
    float* Ob = O + (size_t)bh * HD * SEQ;

    // ---- stage Q (16KB) into kbuf[1] (q-local 0..63) + vbuf[1] (64..127) ----
    #pragma unroll
    for (int i = 0; i < 4; ++i) {
        int slot = tid + 256 * i;
        int region = slot >> 9, s = slot & 511;
        int r = s >> 3, ch1 = s & 7;
        int ch = ch1 ^ (r & 7);                       // pre-swizzled source chunk
        unsigned short* dstb = region ? vbuf[1] : kbuf[1];
        gload16((char*)dstb + s * 16,
                (const char*)(QTb + (size_t)(q0 + region * 64 + r) * HD + ch * 8));
    }
    // ---- stage K0/V0 into buffer 0 ----
    #pragma unroll
    for (int i = 0; i < 2; ++i) {
        int slot = tid + 256 * i;
        int r = slot >> 3, ch1 = slot & 7;
        int ch = ch1 ^ (r & 7);
        gload16((char*)kbuf[0] + slot * 16, (const char*)(KTb + (size_t)r * HD + ch * 8));
        gload16((char*)vbuf[0] + slot * 16, (const char*)(VTb + (size_t)r * SEQ + ch * 8));
    }
    __syncthreads();

    // ---- Q fragments: B[n=q=l31][k-slot (g,j) -> d = 16kk+8g+j] ----
    F8 qf[4];
    {
        const unsigned short* qreg = (w >> 1) ? vbuf[1] : kbuf[1];
        int r = (w & 1) * 32 + l31;
        #pragma unroll
        for (int kk = 0; kk < 4; ++kk)
            qf[kk].s8 = *(const short8*)(qreg + r * 64 + (((2 * kk + g) ^ (r & 7)) * 8));
    }
    __syncthreads();   // Q region free before iter-0 prefetch of tile 1

    f32x16 oacc[2];
    #pragma unroll
    for (int t = 0; t < 2; ++t)
        #pragma unroll
        for (int r = 0; r < 16; ++r) oacc[t][r] = 0.0f;
    float mrun = -1e30f, lrun = 0.0f;

    for (int kt = 0; kt < 16; ++kt) {
        const int cur = kt & 1;
        // ---- prefetch next tile into buf^1 (drained by loop-end barrier) ----
        if (kt < 15) {
            #pragma unroll
            for (int i = 0; i < 2; ++i) {
                int slot = tid + 256 * i;
                int r = slot >> 3, ch1 = slot & 7;
                int ch = ch1 ^ (r & 7);
                gload16((char*)kbuf[cur ^ 1] + slot * 16,
                        (const char*)(KTb + (size_t)((kt + 1) * 64 + r) * HD + ch * 8));
                gload16((char*)vbuf[cur ^ 1] + slot * 16,
                        (const char*)(VTb + (size_t)r * SEQ + (kt + 1) * 64 + ch * 8));
            }
        }
        uint2 mw = *(const uint2*)(BMq + kt * 2);

        // ---- QK^T: sacc[mt] = S^T[key 32mt+rowmap][q=l31] ----
        f32x16 sacc[2];
        #pragma unroll
        for (int t = 0; t < 2; ++t)
            #pragma unroll
            for (int r = 0; r < 16; ++r) sacc[t][r] = 0.0f;
        __builtin_amdgcn_s_setprio(1);
        #pragma unroll
        for (int mt = 0; mt < 2; ++mt) {
            int r = 32 * mt + l31;
            #pragma unroll
            for (int kk = 0; kk < 4; ++kk) {
                F8 kf;
                kf.s8 = *(const short8*)(kbuf[cur] + r * 64 + (((2 * kk + g) ^ (r & 7)) * 8));
                sacc[mt] = __builtin_amdgcn_mfma_f32_32x32x16_bf16(kf.s8, qf[kk].s8, sacc[mt], 0, 0, 0);
            }
        }
        __builtin_amdgcn_s_setprio(0);

        // ---- softmax (exp2 domain; max over ALL incl. masked is valid) ----
        float m0 = sacc[0][0], m1 = sacc[0][1], m2 = sacc[0][2], m3 = sacc[0][3];
        #pragma unroll
        for (int r = 4; r < 16; r += 4) {
            m0 = fmaxf(m0, sacc[0][r]);     m1 = fmaxf(m1, sacc[0][r + 1]);
            m2 = fmaxf(m2, sacc[0][r + 2]); m3 = fmaxf(m3, sacc[0][r + 3]);
        }
        #pragma unroll
        for (int r = 0; r < 16; r += 4) {
            m0 = fmaxf(m0, sacc[1][r]);     m1 = fmaxf(m1, sacc[1][r + 1]);
            m2 = fmaxf(m2, sacc[1][r + 2]); m3 = fmaxf(m3, sacc[1][r + 3]);
        }
        float tmax = fmaxf(fmaxf(m0, m1), fmaxf(m2, m3));
        tmax = fmaxf(tmax, __shfl_xor(tmax, 32));
        // defer-max: only rescale when running max grew past threshold
        if (__any(tmax > mrun + 16.0f)) {
            float mnew = fmaxf(mrun, tmax);
            float ef = ex2(mrun - mnew);
            lrun *= ef;
            #pragma unroll
            for (int t = 0; t < 2; ++t)
                #pragma unroll
                for (int r = 0; r < 16; ++r) oacc[t][r] *= ef;
            mrun = mnew;
        }
        float ls[4] = {0.f, 0.f, 0.f, 0.f};
        #pragma unroll
        for (int mt = 0; mt < 2; ++mt) {
            unsigned mb = (mt ? mw.y : mw.x) >> (g << 2);   // align this half's bits
            #pragma unroll
            for (int r = 0; r < 16; ++r) {
                float pv = ex2(sacc[mt][r] - mrun);          // <= 2^16 via defer
                pv = ((mb >> ((r & 3) + 8 * (r >> 2))) & 1u) ? pv : 0.0f;  // mask->0
                sacc[mt][r] = pv;
                ls[r & 3] += pv;
            }
        }
        float lsum = (ls[0] + ls[1]) + (ls[2] + ls[3]);
        lsum += __shfl_xor(lsum, 32);
        lrun += lsum;

        // ---- pack P to bf16 + cross-half exchange -> PV B-fragments ----
        unsigned PK[2][4][2];
        #pragma unroll
        for (int mt = 0; mt < 2; ++mt)
            #pragma unroll
            for (int c = 0; c < 4; ++c) {
                PK[mt][c][0] = cvt_pk_bf16(sacc[mt][4 * c], sacc[mt][4 * c + 1]);
                PK[mt][c][1] = cvt_pk_bf16(sacc[mt][4 * c + 2], sacc[mt][4 * c + 3]);
            }
        __builtin_amdgcn_s_setprio(1);
        #pragma unroll
        for (int kk = 0; kk < 4; ++kk) {
            const int mt = kk >> 1, c0 = (kk & 1) * 2;
            unsigned u0 = PK[mt][c0][0],     u1 = PK[mt][c0][1];
            unsigned v0 = PK[mt][c0 + 1][0], v1 = PK[mt][c0 + 1][1];
            unsigned ux0 = (unsigned)__shfl_xor((int)u0, 32);
            unsigned ux1 = (unsigned)__shfl_xor((int)u1, 32);
            unsigned vx0 = (unsigned)__shfl_xor((int)v0, 32);
            unsigned vx1 = (unsigned)__shfl_xor((int)v1, 32);
            F8 pb;   // B[n=q][k=key 16kk+8g+j]
            pb.u[0] = g ? vx0 : u0;
            pb.u[1] = g ? vx1 : u1;
            pb.u[2] = g ? v0  : ux0;
            pb.u[3] = g ? v1  : ux1;
            #pragma unroll
            for (int dt = 0; dt < 2; ++dt) {
                int r = 32 * dt + l31;
                F8 vf;   // A[m=d][k=key]
                vf.s8 = *(const short8*)(vbuf[cur] + r * 64 + (((2 * kk + g) ^ (r & 7)) * 8));
                oacc[dt] = __builtin_amdgcn_mfma_f32_32x32x16_bf16(vf.s8, pb.s8, oacc[dt], 0, 0, 0);
            }
        }
        __builtin_amdgcn_s_setprio(0);
        __syncthreads();   // all waves done with buf[cur]; drains prefetch vmem
    }

    // ---- epilogue: O[d][q], d = 32dt + (r&3) + 8(r>>2) + 4g ----
    float inv = 1.0f / lrun;
    #pragma unroll
    for (int dt = 0; dt < 2; ++dt)
        #pragma unroll
        for (int r = 0; r < 16; ++r) {
            int d = 32 * dt + (r & 3) + 8 * (r >> 2) + 4 * g;
            Ob[(size_t)d * SEQ + myq] = oacc[dt][r] * inv;
        }
}

extern "C" void kernel_launch(void* const* d_in, const int* in_sizes, int n_in,
                              void* d_out, int out_size, void* d_ws, size_t ws_size,
                              hipStream_t stream) {
    const float* q = (const float*)d_in[0];
    const float* k = (const float*)d_in[1];
    const float* v = (const float*)d_in[2];
    const float* m = (const float*)d_in[3];
    float* out = (float*)d_out;

    const size_t SZ   = (size_t)64 * SEQ * HD * 2;           // 8 MB per tensor
    const size_t NEED = 3 * SZ + (size_t)8 * SEQ * SEQ / 8;  // 25 MB
    if (ws_size < NEED || d_ws == nullptr) return;           // fail loud (output stays zero)

    unsigned short* QT = (unsigned short*)d_ws;
    unsigned short* KT = (unsigned short*)((char*)d_ws + SZ);
    unsigned short* VT = (unsigned short*)((char*)d_ws + 2 * SZ);
    unsigned*       BM = (unsigned*)((char*)d_ws + 3 * SZ);  // 1 MB of bits

    mha_prep<<<dim3(8192), dim3(256), 0, stream>>>(q, k, v, m, QT, KT, VT, (unsigned char*)BM);
    mha_main<<<dim3(512), dim3(256), 0, stream>>>(QT, KT, VT, BM, out);
}

// Round 9
// 146.565 us; speedup vs baseline: 1.3288x; 1.0525x over previous
//
#include <hip/hip_runtime.h>

// MHA forward, MI355X gfx950. b=8, heads=8 -> bh=64; S=1024; d=64. fp32 in/out.
// Round 9 = round 6 with the two unvalidated constructs replaced:
//   - raw-asm v_permlane32_swap_b32 -> __builtin_amdgcn_permlane32_swap (hazard-safe,
//     defined operand direction; validated pattern per m214v22 / T12 recipe)
//   - __builtin_amdgcn_sbfe -> plain-C -(int)((m>>bit)&1)
// Everything else identical: compile-time LDS addressing, exp2 softmax, defer-max,
// mask-after-exp, XCD swizzle, swizzled gload_lds staging, cvt_pk prep.

#define SEQ 1024
#define HD  64

typedef __attribute__((ext_vector_type(8)))  short short8;
typedef __attribute__((ext_vector_type(8)))  unsigned short us8;
typedef __attribute__((ext_vector_type(16))) float f32x16;
typedef __attribute__((ext_vector_type(2)))  unsigned uint2v;

union F8  { short8 s8; unsigned u[4]; };
union US8 { us8 v; unsigned u[4]; };

__device__ __forceinline__ unsigned cvt_pk_bf16(float lo, float hi) {
    unsigned r;
    asm("v_cvt_pk_bf16_f32 %0, %1, %2" : "=v"(r) : "v"(lo), "v"(hi));
    return r;
}
__device__ __forceinline__ float ex2(float x) {
    float r;
    asm("v_exp_f32 %0, %1" : "=v"(r) : "v"(x));
    return r;
}
// permlane32_swap: a' = [a_lo | b_lo], b' = [a_hi | b_hi]  (across lane<32 / lane>=32)
__device__ __forceinline__ void p32swap(unsigned &a, unsigned &b) {
    uint2v r = __builtin_amdgcn_permlane32_swap(a, b, false, false);
    a = r.x; b = r.y;
}
__device__ __forceinline__ float xhalf_max(float x) {
    unsigned a = __float_as_uint(x), b = __float_as_uint(x);
    p32swap(a, b);
    return fmaxf(__uint_as_float(a), __uint_as_float(b));
}
__device__ __forceinline__ float xhalf_sum(float x) {
    unsigned a = __float_as_uint(x), b = __float_as_uint(x);
    p32swap(a, b);
    return __uint_as_float(a) + __uint_as_float(b);
}
__device__ __forceinline__ void gload16(void* lds, const void* g) {
    __builtin_amdgcn_global_load_lds((const __attribute__((address_space(1))) unsigned*)g,
                                     (__attribute__((address_space(3))) unsigned*)lds,
                                     16, 0, 0);
}

// ============================ prepass ============================
// blocks [0,1024): Q -> QT[q][d] bf16 (scale 0.125*log2e folded)
// blocks [1024,2048): K -> KT[k][d] bf16
// blocks [2048,4096): V -> VT[d][s] bf16 (native)
// blocks [4096,8192): mask -> bitmask (bit=1 keep)
__global__ __launch_bounds__(256)
void mha_prep(const float* __restrict__ Q, const float* __restrict__ K,
              const float* __restrict__ V, const float* __restrict__ M,
              unsigned short* __restrict__ QT, unsigned short* __restrict__ KT,
              unsigned short* __restrict__ VT, unsigned char* __restrict__ BM)
{
    __shared__ float tile[64][68];
    const int bx = blockIdx.x, tid = threadIdx.x;

    if (bx < 2048) {
        const bool isQ = bx < 1024;
        const int id = isQ ? bx : bx - 1024;
        const int bh = id >> 4, st = id & 15;
        const float* src = (isQ ? Q : K) + (size_t)bh * HD * SEQ;
        unsigned short* dst = (isQ ? QT : KT) + (size_t)bh * SEQ * HD;
        const float scale = isQ ? 0.125f * 1.4426950408889634f : 1.0f;
        const int s0 = st * 64;

        // write phase: tile[d][col ^ ((d>>3)<<2)] (16B-aligned XOR swizzle)
        const int d = tid >> 2, sc = tid & 3;
        const int wsw = (d >> 3) << 2;
        #pragma unroll
        for (int i = 0; i < 4; ++i) {
            int col = sc * 4 + i * 16;
            float4 f = *(const float4*)(src + (size_t)d * SEQ + s0 + col);
            f.x *= scale; f.y *= scale; f.z *= scale; f.w *= scale;
            *(float4*)&tile[d][col ^ wsw] = f;
        }
        __syncthreads();
        // read phase: thread (grp,a) reads column s of rows a*8..a*8+7
        const int grp = tid >> 3, a = tid & 7;
        const int rsw = a << 2;
        #pragma unroll
        for (int j = 0; j < 2; ++j) {
            int s = j * 32 + grp;
            int cs = s ^ rsw;
            float v0 = tile[a * 8 + 0][cs], v1 = tile[a * 8 + 1][cs];
            float v2 = tile[a * 8 + 2][cs], v3 = tile[a * 8 + 3][cs];
            float v4 = tile[a * 8 + 4][cs], v5 = tile[a * 8 + 5][cs];
            float v6 = tile[a * 8 + 6][cs], v7 = tile[a * 8 + 7][cs];
            US8 o;
            o.u[0] = cvt_pk_bf16(v0, v1); o.u[1] = cvt_pk_bf16(v2, v3);
            o.u[2] = cvt_pk_bf16(v4, v5); o.u[3] = cvt_pk_bf16(v6, v7);
            *(us8*)(dst + (size_t)(s0 + s) * HD + a * 8) = o.v;
        }
    } else if (bx < 4096) {
        size_t base = ((size_t)(bx - 2048) * 256 + tid) * 8;
        float4 f0 = *(const float4*)(V + base);
        float4 f1 = *(const float4*)(V + base + 4);
        US8 o;
        o.u[0] = cvt_pk_bf16(f0.x, f0.y); o.u[1] = cvt_pk_bf16(f0.z, f0.w);
        o.u[2] = cvt_pk_bf16(f1.x, f1.y); o.u[3] = cvt_pk_bf16(f1.z, f1.w);
        *(us8*)(VT + base) = o.v;
    } else {
        size_t base = ((size_t)(bx - 4096) * 256 + tid) * 8;
        float4 f0 = *(const float4*)(M + base);
        float4 f1 = *(const float4*)(M + base + 4);
        unsigned byte =
            (unsigned)(f0.x > -1.f)        | ((unsigned)(f0.y > -1.f) << 1) |
            ((unsigned)(f0.z > -1.f) << 2) | ((unsigned)(f0.w > -1.f) << 3) |
            ((unsigned)(f1.x > -1.f) << 4) | ((unsigned)(f1.y > -1.f) << 5) |
            ((unsigned)(f1.z > -1.f) << 6) | ((unsigned)(f1.w > -1.f) << 7);
        BM[base >> 3] = (unsigned char)byte;
    }
}

// ============================ main kernel ============================
// Grid 512: bh = (bid&7)*8 + ((bid>>3)&7) (batch per XCD); qt = bid>>6.
// 4 waves x 32 q. Swapped QK^T: mfma(K, Q) -> S^T (col=q). PV: mfma(V, P^T) -> O^T.
// LDS bytes: [0,8K)=K buf0, [8K,16K)=V buf0, [16K,24K)=K buf1, [24K,32K)=V buf1.
__global__ __launch_bounds__(256)
void mha_main(const unsigned short* __restrict__ QT, const unsigned short* __restrict__ KT,
              const unsigned short* __restrict__ VT, const unsigned* __restrict__ BM,
              float* __restrict__ O)
{
    __shared__ __align__(16) unsigned short smem[16384];   // 32 KB
    char* sm = (char*)smem;

    const int bid = blockIdx.x;
    const int qt = bid >> 6;
    const int bh = ((bid & 7) << 3) | ((bid >> 3) & 7);
    const int b  = bh >> 3;
    const int tid = threadIdx.x, w = tid >> 6, lane = tid & 63;
    const int l31 = lane & 31, g = lane >> 5;
    const int q0 = qt * 128;
    const int myq = q0 + w * 32 + l31;

    const char* QTb = (const char*)(QT + (size_t)bh * SEQ * HD);
    const char* KTb = (const char*)(KT + (size_t)bh * SEQ * HD);
    const char* VTb = (const char*)(VT + (size_t)bh * HD * SEQ);
    const unsigned* BMp = BM + ((size_t)b * SEQ + myq) * (SEQ / 32);
    float* Ob = O + (size_t)bh * HD * SEQ;

    // staging source (per-lane, pre-swizzled): row srow, chunk sch
    const int srow = tid >> 3;                      // 0..31
    const int sch  = (tid & 7) ^ (srow & 7);        // XOR involution
    const char* kg = KTb + srow * 128 + sch * 16;   // += 8192/tile; +4096 for half 2
    const char* vg = VTb + srow * 2048 + sch * 16;  // += 128/tile;  +65536 for half 2

    // fragment read bases (bytes): row l31, chunk (2kk+g)^(l31&7)
    int addrK[4];
    #pragma unroll
    for (int kk = 0; kk < 4; ++kk)
        addrK[kk] = l31 * 128 + (((2 * kk + g) ^ (l31 & 7)) * 16);

    // ---- prologue: Q (16KB) -> buf1 regions; K0/V0 -> buf0 ----
    #pragma unroll
    for (int i = 0; i < 4; ++i) {
        int slot = tid + 256 * i;
        int region = slot >> 9, s = slot & 511;
        int r = s >> 3, ch = (s & 7) ^ (r & 7);
        gload16(sm + 16384 + region * 8192 + s * 16,
                QTb + (size_t)(q0 + region * 64 + r) * 128 + ch * 16);
    }
    gload16(sm + tid * 16,                kg);
    gload16(sm + 4096 + tid * 16,         kg + 4096);
    gload16(sm + 8192 + tid * 16,         vg);
    gload16(sm + 12288 + tid * 16,        vg + 65536);
    kg += 8192; vg += 128;
    __syncthreads();

    // Q fragments: B[n=q=l31][k-slot (g,j) -> d = 16kk+8g+j]
    F8 qf[4];
    {
        const char* qbase = sm + 16384 + (w >> 1) * 8192 + (w & 1) * 4096;
        #pragma unroll
        for (int kk = 0; kk < 4; ++kk)
            qf[kk].s8 = *(const short8*)(qbase + addrK[kk]);
    }
    __syncthreads();   // buf1 free before tile-1 prefetch

    f32x16 oacc0, oacc1;
    #pragma unroll
    for (int r = 0; r < 16; ++r) { oacc0[r] = 0.0f; oacc1[r] = 0.0f; }
    float mrun = -1e30f, lrun = 0.0f;

#define TILE(BUFOFF, DSTOFF, DOPREF)                                               \
    {                                                                              \
        if (DOPREF) {                                                              \
            gload16(sm + (DSTOFF) + tid * 16,         kg);                         \
            gload16(sm + (DSTOFF) + 4096 + tid * 16,  kg + 4096);                  \
            gload16(sm + (DSTOFF) + 8192 + tid * 16,  vg);                         \
            gload16(sm + (DSTOFF) + 12288 + tid * 16, vg + 65536);                 \
            kg += 8192; vg += 128;                                                 \
        }                                                                          \
        const uint2 mw = *(const uint2*)BMp; BMp += 2;                             \
        f32x16 sA, sB;                                                             \
        _Pragma("unroll")                                                          \
        for (int r = 0; r < 16; ++r) { sA[r] = 0.0f; sB[r] = 0.0f; }               \
        __builtin_amdgcn_s_setprio(1);                                             \
        _Pragma("unroll")                                                          \
        for (int kk = 0; kk < 4; ++kk) {                                           \
            F8 kf0, kf1;                                                           \
            kf0.s8 = *(const short8*)(sm + (BUFOFF) + addrK[kk]);                  \
            kf1.s8 = *(const short8*)(sm + (BUFOFF) + 4096 + addrK[kk]);           \
            sA = __builtin_amdgcn_mfma_f32_32x32x16_bf16(kf0.s8, qf[kk].s8, sA, 0, 0, 0); \
            sB = __builtin_amdgcn_mfma_f32_32x32x16_bf16(kf1.s8, qf[kk].s8, sB, 0, 0, 0); \
        }                                                                          \
        __builtin_amdgcn_s_setprio(0);                                             \
        float mx0 = fmaxf(sA[0], sB[0]), mx1 = fmaxf(sA[1], sB[1]);                \
        float mx2 = fmaxf(sA[2], sB[2]), mx3 = fmaxf(sA[3], sB[3]);                \
        _Pragma("unroll")                                                          \
        for (int r = 4; r < 16; r += 4) {                                          \
            mx0 = fmaxf(mx0, fmaxf(sA[r],     sB[r]));                             \
            mx1 = fmaxf(mx1, fmaxf(sA[r + 1], sB[r + 1]));                         \
            mx2 = fmaxf(mx2, fmaxf(sA[r + 2], sB[r + 2]));                         \
            mx3 = fmaxf(mx3, fmaxf(sA[r + 3], sB[r + 3]));                         \
        }                                                                          \
        float mx = xhalf_max(fmaxf(fmaxf(mx0, mx1), fmaxf(mx2, mx3)));             \
        if (__any(mx > mrun + 16.0f)) {                                            \
            float mnew = fmaxf(mrun, mx);                                          \
            float ef = ex2(mrun - mnew);                                           \
            lrun *= ef;                                                            \
            _Pragma("unroll")                                                      \
            for (int r = 0; r < 16; ++r) { oacc0[r] *= ef; oacc1[r] *= ef; }       \
            mrun = mnew;                                                           \
        }                                                                          \
        const unsigned mbx = mw.x >> (g << 2);                                     \
        const unsigned mby = mw.y >> (g << 2);                                     \
        float ls0 = 0.f, ls1 = 0.f, ls2 = 0.f, ls3 = 0.f;                          \
        _Pragma("unroll")                                                          \
        for (int r = 0; r < 16; ++r) {                                             \
            const int bit = (r & 3) + 8 * (r >> 2);                                \
            float pa = ex2(sA[r] - mrun);                                          \
            float pb = ex2(sB[r] - mrun);                                          \
            int ma = -(int)((mbx >> bit) & 1u);                                    \
            int mb = -(int)((mby >> bit) & 1u);                                    \
            pa = __uint_as_float(__float_as_uint(pa) & (unsigned)ma);              \
            pb = __uint_as_float(__float_as_uint(pb) & (unsigned)mb);              \
            sA[r] = pa; sB[r] = pb;                                                \
            if ((r & 3) == 0) ls0 += pa + pb;                                      \
            else if ((r & 3) == 1) ls1 += pa + pb;                                 \
            else if ((r & 3) == 2) ls2 += pa + pb;                                 \
            else ls3 += pa + pb;                                                   \
        }                                                                          \
        lrun += xhalf_sum((ls0 + ls1) + (ls2 + ls3));                              \
        unsigned PK0[8], PK1[8];                                                   \
        _Pragma("unroll")                                                          \
        for (int c = 0; c < 4; ++c) {                                              \
            PK0[2 * c]     = cvt_pk_bf16(sA[4 * c],     sA[4 * c + 1]);            \
            PK0[2 * c + 1] = cvt_pk_bf16(sA[4 * c + 2], sA[4 * c + 3]);            \
            PK1[2 * c]     = cvt_pk_bf16(sB[4 * c],     sB[4 * c + 1]);            \
            PK1[2 * c + 1] = cvt_pk_bf16(sB[4 * c + 2], sB[4 * c + 3]);            \
        }                                                                          \
        __builtin_amdgcn_s_setprio(1);                                             \
        _Pragma("unroll")                                                          \
        for (int kk = 0; kk < 4; ++kk) {                                           \
            const int c0 = (kk & 1) * 2;                                           \
            unsigned a0, a1, b0, b1;                                               \
            if (kk < 2) { a0 = PK0[2*c0]; a1 = PK0[2*c0+1]; b0 = PK0[2*c0+2]; b1 = PK0[2*c0+3]; } \
            else        { a0 = PK1[2*c0]; a1 = PK1[2*c0+1]; b0 = PK1[2*c0+2]; b1 = PK1[2*c0+3]; } \
            p32swap(a0, b0);                                                       \
            p32swap(a1, b1);                                                       \
            F8 pbf; pbf.u[0] = a0; pbf.u[1] = a1; pbf.u[2] = b0; pbf.u[3] = b1;    \
            F8 vf0, vf1;                                                           \
            vf0.s8 = *(const short8*)(sm + (BUFOFF) + 8192 + addrK[kk]);           \
            vf1.s8 = *(const short8*)(sm + (BUFOFF) + 12288 + addrK[kk]);          \
            oacc0 = __builtin_amdgcn_mfma_f32_32x32x16_bf16(vf0.s8, pbf.s8, oacc0, 0, 0, 0); \
            oacc1 = __builtin_amdgcn_mfma_f32_32x32x16_bf16(vf1.s8, pbf.s8, oacc1, 0, 0, 0); \
        }                                                                          \
        __builtin_amdgcn_s_setprio(0);                                             \
        __syncthreads();                                                           \
    }

    #pragma unroll 1
    for (int kt2 = 0; kt2 < 8; ++kt2) {
        TILE(0, 16384, 1)
        TILE(16384, 0, (kt2 < 7))
    }
#undef TILE

    // ---- epilogue: O[d][q], d = (r&3) + 8*(r>>2) + 4g  (+32 for oacc1) ----
    float inv = 1.0f / lrun;
    #pragma unroll
    for (int r = 0; r < 16; ++r) {
        int d = (r & 3) + 8 * (r >> 2) + 4 * g;
        Ob[(size_t)d * SEQ + myq] = oacc0[r] * inv;
        Ob[(size_t)(d + 32) * SEQ + myq] = oacc1[r] * inv;
    }
}

extern "C" void kernel_launch(void* const* d_in, const int* in_sizes, int n_in,
                              void* d_out, int out_size, void* d_ws, size_t ws_size,
                              hipStream_t stream) {
    const float* q = (const float*)d_in[0];
    const float* k = (const float*)d_in[1];
    const float* v = (const float*)d_in[2];
    const float* m = (const float*)d_in[3];
    float* out = (float*)d_out;

    const size_t SZ   = (size_t)64 * SEQ * HD * 2;           // 8 MB per tensor
    const size_t NEED = 3 * SZ + (size_t)8 * SEQ * SEQ / 8;  // 25 MB
    if (ws_size < NEED || d_ws == nullptr) return;

    unsigned short* QT = (unsigned short*)d_ws;
    unsigned short* KT = (unsigned short*)((char*)d_ws + SZ);
    unsigned short* VT = (unsigned short*)((char*)d_ws + 2 * SZ);
    unsigned*       BM = (unsigned*)((char*)d_ws + 3 * SZ);

    mha_prep<<<dim3(8192), dim3(256), 0, stream>>>(q, k, v, m, QT, KT, VT, (unsigned char*)BM);
    mha_main<<<dim3(512), dim3(256), 0, stream>>>(QT, KT, VT, BM, out);
}

// Round 10
// 140.503 us; speedup vs baseline: 1.3861x; 1.0431x over previous
//
#include <hip/hip_runtime.h>

// MHA forward, MI355X gfx950. b=8, heads=8 -> bh=64; S=1024; d=64. fp32 in/out.
// Round 10: FUSED kernel — no Q/K/V prep. Main reads fp32 directly:
//   K/V reg-staged per tile (float4 loads + cvt_pk + swizzled ds_write),
//   Q fragments built from global (once per block, scale*log2e folded).
// Only a 1MB mask->bitmask mini-prep remains (coalesced).
// LDS read side / softmax / permlane exchange / epilogue identical to the
// HW-validated round-9 kernel.

#define SEQ 1024
#define HD  64

typedef __attribute__((ext_vector_type(8)))  short short8;
typedef __attribute__((ext_vector_type(16))) float f32x16;
typedef __attribute__((ext_vector_type(2)))  unsigned uint2v;

union F8 { short8 s8; unsigned u[4]; };

__device__ __forceinline__ unsigned cvt_pk_bf16(float lo, float hi) {
    unsigned r;
    asm("v_cvt_pk_bf16_f32 %0, %1, %2" : "=v"(r) : "v"(lo), "v"(hi));
    return r;
}
__device__ __forceinline__ float ex2(float x) {
    float r;
    asm("v_exp_f32 %0, %1" : "=v"(r) : "v"(x));
    return r;
}
// permlane32_swap: a' = [a_lo | b_lo], b' = [a_hi | b_hi] (across lane<32 / >=32)
__device__ __forceinline__ void p32swap(unsigned &a, unsigned &b) {
    uint2v r = __builtin_amdgcn_permlane32_swap(a, b, false, false);
    a = r.x; b = r.y;
}
__device__ __forceinline__ float xhalf_max(float x) {
    unsigned a = __float_as_uint(x), b = __float_as_uint(x);
    p32swap(a, b);
    return fmaxf(__uint_as_float(a), __uint_as_float(b));
}
__device__ __forceinline__ float xhalf_sum(float x) {
    unsigned a = __float_as_uint(x), b = __float_as_uint(x);
    p32swap(a, b);
    return __uint_as_float(a) + __uint_as_float(b);
}

// ============================ mask mini-prep ============================
// mask (b,q,k) fp32 {0,-10000} -> bitmask, bit=1 keep. 33.5MB read, 1MB write.
__global__ __launch_bounds__(256)
void mask_prep(const float* __restrict__ M, unsigned char* __restrict__ BM)
{
    size_t base = ((size_t)blockIdx.x * 256 + threadIdx.x) * 8;
    float4 f0 = *(const float4*)(M + base);
    float4 f1 = *(const float4*)(M + base + 4);
    unsigned byte =
        (unsigned)(f0.x > -1.f)        | ((unsigned)(f0.y > -1.f) << 1) |
        ((unsigned)(f0.z > -1.f) << 2) | ((unsigned)(f0.w > -1.f) << 3) |
        ((unsigned)(f1.x > -1.f) << 4) | ((unsigned)(f1.y > -1.f) << 5) |
        ((unsigned)(f1.z > -1.f) << 6) | ((unsigned)(f1.w > -1.f) << 7);
    BM[base >> 3] = (unsigned char)byte;
}

// ============================ fused main ============================
// Grid 512: bh = (bid&7)*8 + ((bid>>3)&7) (batch per XCD); qt = bid>>6.
// 4 waves x 32 q. Swapped QK^T: mfma(K, Q) -> S^T (col=q). PV: mfma(V, P^T) -> O^T.
// LDS: buf0 [0,16K) = K 8KB | V 8KB ; buf1 [16K,32K) same.
// K LDS: row=key, chunk c holds d = 8*(c^(key&7)) + j  (j = byte/2 within chunk)
// V LDS: row=d,   chunk c holds key = 8*(c^(d&7)) + j
__global__ __launch_bounds__(256)
void mha_fused(const float* __restrict__ Q, const float* __restrict__ K,
               const float* __restrict__ V, const unsigned* __restrict__ BM,
               float* __restrict__ O)
{
    __shared__ __align__(16) char sm[32768];

    const int bid = blockIdx.x;
    const int qt = bid >> 6;
    const int bh = ((bid & 7) << 3) | ((bid >> 3) & 7);
    const int b  = bh >> 3;
    const int tid = threadIdx.x, w = tid >> 6, lane = tid & 63;
    const int l31 = lane & 31, g = lane >> 5;
    const int q0 = qt * 128;
    const int myq = q0 + w * 32 + l31;

    const float* Qb = Q + (size_t)bh * HD * SEQ;
    const float* Kb = K + (size_t)bh * HD * SEQ;
    const float* Vb = V + (size_t)bh * HD * SEQ;
    const unsigned* BMp = BM + ((size_t)b * SEQ + myq) * (SEQ / 32);
    float* Ob = O + (size_t)bh * HD * SEQ;

    // staging thread mapping: thread -> (d-row sd, float4 slot base sf)
    const int sd = tid >> 2;          // 0..63
    const int sf = tid & 3;           // 0..3 ; covers slots sf+4i, i=0..3
    const float* krow = Kb + (size_t)sd * SEQ;
    const float* vrow = Vb + (size_t)sd * SEQ;
    // K write per (key kc, d=sd): byte = kc*128 + ((sd>>3)^(kc&7))*16 + (sd&7)*2
    const int ksd_hi = sd >> 3, ksd_lo2 = (sd & 7) << 1, vsw = sd & 7;

    // fragment read bases (identical to round 9)
    int addrK[4];
    #pragma unroll
    for (int kk = 0; kk < 4; ++kk)
        addrK[kk] = l31 * 128 + (((2 * kk + g) ^ (l31 & 7)) * 16);

    // ---- Q fragments direct from global: B[n=q=l31][k-slot (g,j) -> d=16kk+8g+j] ----
    const float qscale = 0.125f * 1.4426950408889634f;
    F8 qf[4];
    #pragma unroll
    for (int kk = 0; kk < 4; ++kk)
        #pragma unroll
        for (int i = 0; i < 4; ++i) {
            float a = Qb[(size_t)(16 * kk + 8 * g + 2 * i)     * SEQ + myq] * qscale;
            float c = Qb[(size_t)(16 * kk + 8 * g + 2 * i + 1) * SEQ + myq] * qscale;
            qf[kk].u[i] = cvt_pk_bf16(a, c);
        }

    float4 kr[4], vr[4];
#define STAGE_LOAD(NKT)                                                            \
    {                                                                              \
        _Pragma("unroll")                                                          \
        for (int i = 0; i < 4; ++i) {                                              \
            int cb = (NKT) * 64 + (sf + 4 * i) * 4;                                \
            kr[i] = *(const float4*)(krow + cb);                                   \
            vr[i] = *(const float4*)(vrow + cb);                                   \
        }                                                                          \
    }
#define STAGE_WRITE(TB)                                                            \
    {                                                                              \
        char* base = sm + (TB);                                                    \
        _Pragma("unroll")                                                          \
        for (int i = 0; i < 4; ++i) {                                              \
            int kcb = (sf + 4 * i) * 4;                                            \
            /* V: one b64 (4 consecutive keys, same chunk) */                      \
            unsigned pv0 = cvt_pk_bf16(vr[i].x, vr[i].y);                          \
            unsigned pv1 = cvt_pk_bf16(vr[i].z, vr[i].w);                          \
            uint2 vv; vv.x = pv0; vv.y = pv1;                                      \
            *(uint2*)(base + 8192 + sd * 128 + ((((kcb >> 3) ^ vsw)) << 4)         \
                      + ((kcb & 7) << 1)) = vv;                                    \
            /* K: four b16 scatter (4 key-rows, same d) */                         \
            unsigned c0 = cvt_pk_bf16(kr[i].x, kr[i].y);                           \
            unsigned c1 = cvt_pk_bf16(kr[i].z, kr[i].w);                           \
            *(unsigned short*)(base + (kcb + 0) * 128 +                            \
                ((ksd_hi ^ ((kcb + 0) & 7)) << 4) + ksd_lo2) = (unsigned short)c0; \
            *(unsigned short*)(base + (kcb + 1) * 128 +                            \
                ((ksd_hi ^ ((kcb + 1) & 7)) << 4) + ksd_lo2) = (unsigned short)(c0 >> 16); \
            *(unsigned short*)(base + (kcb + 2) * 128 +                            \
                ((ksd_hi ^ ((kcb + 2) & 7)) << 4) + ksd_lo2) = (unsigned short)c1; \
            *(unsigned short*)(base + (kcb + 3) * 128 +                            \
                ((ksd_hi ^ ((kcb + 3) & 7)) << 4) + ksd_lo2) = (unsigned short)(c1 >> 16); \
        }                                                                          \
    }

    // ---- prologue: tile 0 ----
    STAGE_LOAD(0)
    STAGE_WRITE(0)
    __syncthreads();

    f32x16 oacc0, oacc1;
    #pragma unroll
    for (int r = 0; r < 16; ++r) { oacc0[r] = 0.0f; oacc1[r] = 0.0f; }
    float mrun = -1e30f, lrun = 0.0f;

#define TILE(BUFOFF, WOFF, NKT, DOPREF)                                            \
    {                                                                              \
        if (DOPREF) STAGE_LOAD(NKT)                                                \
        const uint2 mw = *(const uint2*)BMp; BMp += 2;                             \
        f32x16 sA, sB;                                                             \
        _Pragma("unroll")                                                          \
        for (int r = 0; r < 16; ++r) { sA[r] = 0.0f; sB[r] = 0.0f; }               \
        __builtin_amdgcn_s_setprio(1);                                             \
        _Pragma("unroll")                                                          \
        for (int kk = 0; kk < 4; ++kk) {                                           \
            F8 kf0, kf1;                                                           \
            kf0.s8 = *(const short8*)(sm + (BUFOFF) + addrK[kk]);                  \
            kf1.s8 = *(const short8*)(sm + (BUFOFF) + 4096 + addrK[kk]);           \
            sA = __builtin_amdgcn_mfma_f32_32x32x16_bf16(kf0.s8, qf[kk].s8, sA, 0, 0, 0); \
            sB = __builtin_amdgcn_mfma_f32_32x32x16_bf16(kf1.s8, qf[kk].s8, sB, 0, 0, 0); \
        }                                                                          \
        __builtin_amdgcn_s_setprio(0);                                             \
        float mx0 = fmaxf(sA[0], sB[0]), mx1 = fmaxf(sA[1], sB[1]);                \
        float mx2 = fmaxf(sA[2], sB[2]), mx3 = fmaxf(sA[3], sB[3]);                \
        _Pragma("unroll")                                                          \
        for (int r = 4; r < 16; r += 4) {                                          \
            mx0 = fmaxf(mx0, fmaxf(sA[r],     sB[r]));                             \
            mx1 = fmaxf(mx1, fmaxf(sA[r + 1], sB[r + 1]));                         \
            mx2 = fmaxf(mx2, fmaxf(sA[r + 2], sB[r + 2]));                         \
            mx3 = fmaxf(mx3, fmaxf(sA[r + 3], sB[r + 3]));                         \
        }                                                                          \
        float mx = xhalf_max(fmaxf(fmaxf(mx0, mx1), fmaxf(mx2, mx3)));             \
        if (__any(mx > mrun + 16.0f)) {                                            \
            float mnew = fmaxf(mrun, mx);                                          \
            float ef = ex2(mrun - mnew);                                           \
            lrun *= ef;                                                            \
            _Pragma("unroll")                                                      \
            for (int r = 0; r < 16; ++r) { oacc0[r] *= ef; oacc1[r] *= ef; }       \
            mrun = mnew;                                                           \
        }                                                                          \
        const unsigned mbx = mw.x >> (g << 2);                                     \
        const unsigned mby = mw.y >> (g << 2);                                     \
        float ls0 = 0.f, ls1 = 0.f, ls2 = 0.f, ls3 = 0.f;                          \
        _Pragma("unroll")                                                          \
        for (int r = 0; r < 16; ++r) {                                             \
            const int bit = (r & 3) + 8 * (r >> 2);                                \
            float pa = ex2(sA[r] - mrun);                                          \
            float pb = ex2(sB[r] - mrun);                                          \
            int ma = -(int)((mbx >> bit) & 1u);                                    \
            int mb = -(int)((mby >> bit) & 1u);                                    \
            pa = __uint_as_float(__float_as_uint(pa) & (unsigned)ma);              \
            pb = __uint_as_float(__float_as_uint(pb) & (unsigned)mb);              \
            sA[r] = pa; sB[r] = pb;                                                \
            if ((r & 3) == 0) ls0 += pa + pb;                                      \
            else if ((r & 3) == 1) ls1 += pa + pb;                                 \
            else if ((r & 3) == 2) ls2 += pa + pb;                                 \
            else ls3 += pa + pb;                                                   \
        }                                                                          \
        lrun += xhalf_sum((ls0 + ls1) + (ls2 + ls3));                              \
        unsigned PK0[8], PK1[8];                                                   \
        _Pragma("unroll")                                                          \
        for (int c = 0; c < 4; ++c) {                                              \
            PK0[2 * c]     = cvt_pk_bf16(sA[4 * c],     sA[4 * c + 1]);            \
            PK0[2 * c + 1] = cvt_pk_bf16(sA[4 * c + 2], sA[4 * c + 3]);            \
            PK1[2 * c]     = cvt_pk_bf16(sB[4 * c],     sB[4 * c + 1]);            \
            PK1[2 * c + 1] = cvt_pk_bf16(sB[4 * c + 2], sB[4 * c + 3]);            \
        }                                                                          \
        __builtin_amdgcn_s_setprio(1);                                             \
        _Pragma("unroll")                                                          \
        for (int kk = 0; kk < 4; ++kk) {                                           \
            const int c0 = (kk & 1) * 2;                                           \
            unsigned a0, a1, b0, b1;                                               \
            if (kk < 2) { a0 = PK0[2*c0]; a1 = PK0[2*c0+1]; b0 = PK0[2*c0+2]; b1 = PK0[2*c0+3]; } \
            else        { a0 = PK1[2*c0]; a1 = PK1[2*c0+1]; b0 = PK1[2*c0+2]; b1 = PK1[2*c0+3]; } \
            p32swap(a0, b0);                                                       \
            p32swap(a1, b1);                                                       \
            F8 pbf; pbf.u[0] = a0; pbf.u[1] = a1; pbf.u[2] = b0; pbf.u[3] = b1;    \
            F8 vf0, vf1;                                                           \
            vf0.s8 = *(const short8*)(sm + (BUFOFF) + 8192 + addrK[kk]);           \
            vf1.s8 = *(const short8*)(sm + (BUFOFF) + 12288 + addrK[kk]);          \
            oacc0 = __builtin_amdgcn_mfma_f32_32x32x16_bf16(vf0.s8, pbf.s8, oacc0, 0, 0, 0); \
            oacc1 = __builtin_amdgcn_mfma_f32_32x32x16_bf16(vf1.s8, pbf.s8, oacc1, 0, 0, 0); \
        }                                                                          \
        __builtin_amdgcn_s_setprio(0);                                             \
        if (DOPREF) STAGE_WRITE(WOFF)                                              \
        __syncthreads();                                                           \
    }

    #pragma unroll 1
    for (int kt2 = 0; kt2 < 8; ++kt2) {
        TILE(0, 16384, kt2 * 2 + 1, true)
        TILE(16384, 0, kt2 * 2 + 2, (kt2 < 7))
    }
#undef TILE
#undef STAGE_LOAD
#undef STAGE_WRITE

    // ---- epilogue: O[d][q], d = (r&3) + 8*(r>>2) + 4g (+32 for oacc1) ----
    float inv = 1.0f / lrun;
    #pragma unroll
    for (int r = 0; r < 16; ++r) {
        int d = (r & 3) + 8 * (r >> 2) + 4 * g;
        Ob[(size_t)d * SEQ + myq] = oacc0[r] * inv;
        Ob[(size_t)(d + 32) * SEQ + myq] = oacc1[r] * inv;
    }
}

extern "C" void kernel_launch(void* const* d_in, const int* in_sizes, int n_in,
                              void* d_out, int out_size, void* d_ws, size_t ws_size,
                              hipStream_t stream) {
    const float* q = (const float*)d_in[0];
    const float* k = (const float*)d_in[1];
    const float* v = (const float*)d_in[2];
    const float* m = (const float*)d_in[3];
    float* out = (float*)d_out;

    const size_t NEED = (size_t)SEQ * SEQ;   // 1 MB of mask bits (8 batches / 8 bits)
    if (ws_size < NEED || d_ws == nullptr) return;
    unsigned* BM = (unsigned*)d_ws;

    mask_prep<<<dim3(4096), dim3(256), 0, stream>>>(m, (unsigned char*)BM);
    mha_fused<<<dim3(512), dim3(256), 0, stream>>>(q, k, v, BM, out);
}